// Round 11
// baseline (334.845 us; speedup 1.0000x reference)
//
#include <hip/hip_runtime.h>
#include <hip/hip_bf16.h>
#include <stdint.h>

#define IN_DIM 4096
#define OUT_DIM 4096
#define M_ROWS 8192   // 4 * 2048

typedef __attribute__((ext_vector_type(8))) short s16x8;
typedef __attribute__((ext_vector_type(4))) float f32x4;

__device__ __forceinline__ unsigned short f2bf(float f) {
  uint32_t u = __float_as_uint(f);
  uint32_t r = (u + 0x7fffu + ((u >> 16) & 1u)) >> 16;  // RNE
  return (unsigned short)r;
}
__device__ __forceinline__ float b2f(unsigned short u) {
  return __uint_as_float((uint32_t)u << 16);
}

__device__ __forceinline__ void async16(void* lds, const void* g) {
  __builtin_amdgcn_global_load_lds(
      (const __attribute__((address_space(1))) unsigned int*)g,
      (__attribute__((address_space(3))) unsigned int*)lds, 16, 0, 0);
}

#define FENCE asm volatile("" ::: "memory")

// in-register H16 (4 radix-2 stages, all indices compile-time)
__device__ __forceinline__ void h16(float (&v)[16]) {
#pragma unroll
  for (int h = 1; h < 16; h <<= 1) {
#pragma unroll
    for (int g = 0; g < 8; ++g) {
      int r = g & (h - 1);
      int i0 = ((g & ~(h - 1)) << 1) | r;
      float a = v[i0], b = v[i0 + h];
      v[i0] = a + b;
      v[i0 + h] = a - b;
    }
  }
}

// radix-4 butterfly over t[64][65] columns
#define W_RADIX4(TARR)                                                     \
  for (int h = 1; h < 64; h <<= 2) {                                       \
    __syncthreads();                                                       \
    _Pragma("unroll") for (int j = 0; j < 4; ++j) {                        \
      int g2 = j * 256 + tid;                                              \
      int c = g2 & 63, u = g2 >> 6;                                        \
      int r = u & (h - 1);                                                 \
      int i0 = ((u & ~(h - 1)) << 2) | r;                                  \
      float a = TARR[i0][c], b2 = TARR[i0 + h][c];                         \
      float c2 = TARR[i0 + 2 * h][c], d = TARR[i0 + 3 * h][c];             \
      float y0 = a + b2, y1 = a - b2, y2 = c2 + d, y3 = c2 - d;            \
      TARR[i0][c] = y0 + y2;                                               \
      TARR[i0 + h][c] = y1 + y3;                                           \
      TARR[i0 + 2 * h][c] = y0 - y2;                                       \
      TARR[i0 + 3 * h][c] = y1 - y3;                                       \
    }                                                                      \
  }                                                                        \
  __syncthreads();

// ---- K1: fwht_x (blocks 0..8191) || trellis-decode + inner W-FWHT (8192..12287)
// w_inner blocks remapped so each ohi-group's 64 blocks land on ONE XCD
// (trellis rows shared by the group -> L2 line fetched once per group).
__global__ __launch_bounds__(256) void pre1_kernel(
    const float* __restrict__ x, const float* __restrict__ SU,
    unsigned short* __restrict__ xh,
    const int* __restrict__ trellis, unsigned short* __restrict__ wdec) {
  __shared__ __align__(16) char smem[17408];
  const int tid = threadIdx.x;
  if (blockIdx.x < 8192) {
    // ---------- xh = bf16(fwht(x * SU)) = H16 (x) H16 (x) H16, one row ----------
    float* s = (float*)smem;  // padded: addr(i) = i + (i>>4), 4352 floats
    const int row = blockIdx.x;
    const int t = tid;
    float v[16];
    const float* xr = x + (size_t)row * IN_DIM;
#pragma unroll
    for (int a = 0; a < 16; ++a) {
      int i = a * 256 + t;
      v[a] = __builtin_nontemporal_load(&xr[i]) * SU[i];  // x: single-use stream
    }
    h16(v);  // over a
#pragma unroll
    for (int a = 0; a < 16; ++a) {
      int i = a * 256 + t;
      s[i + (i >> 4)] = v[a];
    }
    __syncthreads();
    const int A = t >> 4, C = t & 15;
#pragma unroll
    for (int b = 0; b < 16; ++b) {
      int i = A * 256 + b * 16 + C;
      v[b] = s[i + (i >> 4)];
    }
    h16(v);  // over b
    __syncthreads();
#pragma unroll
    for (int b = 0; b < 16; ++b) {
      int i = A * 256 + b * 16 + C;
      s[i + (i >> 4)] = v[b];
    }
    __syncthreads();
#pragma unroll
    for (int c = 0; c < 16; ++c) {
      int i = t * 16 + c;
      v[c] = s[i + (i >> 4)];
    }
    h16(v);  // over c
    unsigned short ob[16];
#pragma unroll
    for (int c = 0; c < 16; ++c) ob[c] = f2bf(v[c] * 0.015625f);
    s16x8* dst = (s16x8*)(xh + (size_t)row * IN_DIM + t * 16);
    dst[0] = *(s16x8*)&ob[0];
    dst[1] = *(s16x8*)&ob[8];
  } else {
    // ---------- trellis decode + FWHT over OUT bits 0..5 (bf16 out) ----------
    float (*t)[65] = (float(*)[65])smem;  // 64x65 floats
    const int b2 = blockIdx.x - 8192;     // 0..4095
    // XCD-group remap: ohi's 64 blocks all have b2 % 8 == ohi % 8 -> same XCD
    const int slot = b2 & 7;
    const int q = b2 >> 3;          // 0..511
    const int it = q & 63;
    const int ohi = (q >> 6) * 8 + slot;
    const float g = 0.44721359549995793f;  // 1/sqrt(5)
#pragma unroll
    for (int j = 0; j < 2; ++j) {
      int wi = j * 256 + tid;
      int r = wi >> 3, wc = wi & 7;
      int word = __builtin_nontemporal_load(
          &trellis[(size_t)(ohi * 64 + r) * 512 + it * 8 + wc]);
#pragma unroll
      for (int jj = 0; jj < 8; ++jj) {
        int code = (word >> (14 - 2 * jj)) & 3;
        t[r][wc * 8 + jj] = (float)(2 * code - 3) * g;
      }
    }
    W_RADIX4(t)
#pragma unroll
    for (int j = 0; j < 16; ++j) {
      int e = j * 256 + tid;
      int r = e >> 6, c = e & 63;
      wdec[((size_t)(ohi * 64 + r)) * IN_DIM + it * 64 + c] = f2bf(t[r][c]);
    }
  }
}

// ---- K2: per-channel min/max partials (blocks 0..255) || outer W-FWHT (256..4351)
__global__ __launch_bounds__(256) void pre2_kernel(
    const unsigned short* __restrict__ xh,
    float* __restrict__ pmin, float* __restrict__ pmax,
    const unsigned short* __restrict__ wdec, const float* __restrict__ SV,
    const float* __restrict__ wscale, unsigned short* __restrict__ wq) {
  __shared__ __align__(16) char smem[16640];
  const int tid = threadIdx.x;
  if (blockIdx.x < 256) {
    // ---------- min/max over 256-row chunk, 2 channels/thread ----------
    const int rc = blockIdx.x >> 3;   // 0..31 row-chunk of 256 rows
    const int cb = blockIdx.x & 7;    // 0..7 channel block of 512
    const int ch0 = cb * 512 + tid * 2;
    float mn0 = 3.4e38f, mx0 = -3.4e38f, mn1 = 3.4e38f, mx1 = -3.4e38f;
    const unsigned int* base =
        (const unsigned int*)(xh + (size_t)rc * 256 * IN_DIM + ch0);
    for (int r = 0; r < 256; ++r) {
      unsigned int u = base[(size_t)r * (IN_DIM / 2)];
      float v0 = __uint_as_float(u << 16);
      float v1 = __uint_as_float(u & 0xffff0000u);
      mn0 = fminf(mn0, v0); mx0 = fmaxf(mx0, v0);
      mn1 = fminf(mn1, v1); mx1 = fmaxf(mx1, v1);
    }
    pmin[rc * IN_DIM + ch0] = mn0;
    pmin[rc * IN_DIM + ch0 + 1] = mn1;
    pmax[rc * IN_DIM + ch0] = mx0;
    pmax[rc * IN_DIM + ch0 + 1] = mx1;
  } else {
    // ---------- FWHT over OUT bits 6..11 + 1/64 + SV + group scales ----------
    float (*t)[65] = (float(*)[65])smem;
    const int b = blockIdx.x - 256;
    const int olo = b >> 6;
    const int it  = b & 63;
#pragma unroll
    for (int j = 0; j < 16; ++j) {
      int e = j * 256 + tid;
      int r = e >> 6, c = e & 63;
      t[r][c] = b2f(__builtin_nontemporal_load(
          &wdec[((size_t)(r * 64 + olo)) * IN_DIM + it * 64 + c]));  // last use
    }
    W_RADIX4(t)
#pragma unroll
    for (int j = 0; j < 16; ++j) {
      int e = j * 256 + tid;
      int r = e >> 6, c = e & 63;
      int o = r * 64 + olo;
      int i = it * 64 + c;
      float val = t[r][c] * 0.015625f * SV[o] * wscale[(o << 4) + (i >> 8)];
      wq[(size_t)o * IN_DIM + i] = f2bf(val);
    }
  }
}

// ---------------- K3: reduce partials -> scale/zero ----------------
__global__ void minmax_fin_kernel(const float* __restrict__ pmin, const float* __restrict__ pmax,
                                  float* __restrict__ scale, float* __restrict__ zero) {
  int ch = blockIdx.x * 256 + threadIdx.x;
  float mn = 3.4e38f, mx = -3.4e38f;
  for (int rc = 0; rc < 32; ++rc) {
    mn = fminf(mn, pmin[rc * IN_DIM + ch]);
    mx = fmaxf(mx, pmax[rc * IN_DIM + ch]);
  }
  float sc = fmaxf((mx - mn) / 255.0f, 1e-8f);
  float zp = rintf(-mn / sc);  // rintf = half-to-even = jnp.round
  scale[ch] = sc;
  zero[ch] = zp;
}

// ---------------- K4: fake-quant + bf16 cast ----------------
__global__ void quant_kernel(const unsigned short* __restrict__ xh,
                             const float* __restrict__ scale, const float* __restrict__ zero,
                             unsigned short* __restrict__ xq) {
  const int total8 = M_ROWS * IN_DIM / 8;
  for (int i8 = blockIdx.x * blockDim.x + threadIdx.x; i8 < total8;
       i8 += gridDim.x * blockDim.x) {
    int c8 = i8 & (IN_DIM / 8 - 1);
    s16x8 v = __builtin_nontemporal_load(&((const s16x8*)xh)[i8]);  // last use of xh
    unsigned short o[8];
#pragma unroll
    for (int j = 0; j < 8; ++j) {
      float sc = scale[c8 * 8 + j];
      float zp = zero[c8 * 8 + j];
      float f = b2f((unsigned short)v[j]);
      float q = fminf(fmaxf(rintf(f / sc) + zp, 0.f), 255.f);
      o[j] = f2bf((q - zp) * sc);
    }
    ((s16x8*)xq)[i8] = *(s16x8*)&o[0];
  }
}

// ---------------- K5: 256x256 8-phase bf16 GEMM (round-6 proven) ----------
// C stores nontemporal: keep xq/wq L3-resident (128 MB C stream was evicting
// the 96 MB operand set -> 302 MB HBM fetch vs 96 unique).
__global__ __launch_bounds__(512, 2) void gemm256_kernel(
    const unsigned short* __restrict__ A, const unsigned short* __restrict__ B,
    float* __restrict__ C) {
  __shared__ __align__(16) unsigned short lds[65536];  // 128 KiB
  const int tid  = threadIdx.x;
  const int lane = tid & 63;
  const int wave = tid >> 6;
  const int wm = wave >> 2, wn = wave & 3;
  const int fr = lane & 15, kqi = lane >> 4;
  const int swz = fr & 7;

  // XCD-aware bijective swizzle (nwg=512, 512%8==0)
  const int b  = blockIdx.x;
  const int wg = (b & 7) * 64 + (b >> 3);
  const int bm = wg >> 4, bn = wg & 15;
  const int gm0 = bm * 256, gn0 = bn * 256;

  f32x4 acc[2][2][4][2] = {};  // [qm][qn][mi][ni]
  s16x8 af0[4][2], af1[4][2];  // QM0 / QM1 fragment buffers [mi][kk]
  s16x8 bf0[2][2], bf1[2][2];  // QN0 / QN1 fragment buffers [ni][kk]

  const int F0 = tid, F1 = 512 + tid;
  const int rh0 = F0 >> 3, s0 = (F0 & 7) ^ (rh0 & 7);
  const int rh1 = F1 >> 3, s1 = (F1 & 7) ^ (rh1 & 7);
  auto stage = [&](const unsigned short* gbase, int grow0, int kcol, int ldsoff) {
    async16((void*)&lds[ldsoff + F0 * 8],
            (const void*)(gbase + (size_t)(grow0 + rh0) * IN_DIM + kcol + s0 * 8));
    async16((void*)&lds[ldsoff + F1 * 8],
            (const void*)(gbase + (size_t)(grow0 + rh1) * IN_DIM + kcol + s1 * 8));
  };

#define READ_AF2(DST, QM, TBUF, MIH)                                                      \
  {                                                                                       \
    const int abase = (TBUF) * 16384 + (QM) * 8192;                                       \
    _Pragma("unroll") for (int kk = 0; kk < 2; ++kk)                                      \
      _Pragma("unroll") for (int mi = 2 * (MIH); mi < 2 * (MIH) + 2; ++mi) {              \
        int rh = wm * 64 + mi * 16 + fr;                                                  \
        DST[mi][kk] = *(const s16x8*)&lds[abase + rh * 64 + (((kk * 4 + kqi) ^ swz) * 8)];\
      }                                                                                   \
  }
#define READ_BF2(DST, QN, TBUF, NI)                                                       \
  {                                                                                       \
    const int bbase = 32768 + (TBUF) * 16384 + (QN) * 8192;                               \
    const int rh = wn * 32 + (NI) * 16 + fr;                                              \
    _Pragma("unroll") for (int kk = 0; kk < 2; ++kk)                                      \
      DST[NI][kk] = *(const s16x8*)&lds[bbase + rh * 64 + (((kk * 4 + kqi) ^ swz) * 8)];  \
  }
#define MFMA16(QM, QN, AF, BF)                                                            \
    _Pragma("unroll") for (int kk = 0; kk < 2; ++kk)                                      \
      _Pragma("unroll") for (int mi = 0; mi < 4; ++mi)                                    \
        _Pragma("unroll") for (int ni = 0; ni < 2; ++ni)                                  \
          acc[QM][QN][mi][ni] = __builtin_amdgcn_mfma_f32_16x16x32_bf16(                  \
              AF[mi][kk], BF[ni][kk], acc[QM][QN][mi][ni], 0, 0, 0);
#define PHASE_BEGIN(SGBASE, SGROW0, SKCOL, SLDSOFF, VM)                                   \
    stage(SGBASE, SGROW0, SKCOL, SLDSOFF);                                                \
    FENCE;                                                                                \
    asm volatile("s_waitcnt vmcnt(" #VM ")" ::: "memory");                                \
    __builtin_amdgcn_s_barrier();                                                         \
    FENCE;                                                                                \
    __builtin_amdgcn_s_setprio(1);
#define PHASE_END                                                                         \
    __builtin_amdgcn_s_setprio(0);                                                        \
    FENCE;                                                                                \
    __builtin_amdgcn_s_barrier();                                                         \
    FENCE;

  // prologue: stage T0 fully + T1 half0s; vmcnt(8) completes T0.A-H0/B-H0
  stage(A, gm0,       0, 0);       // T0.A-H0 -> buf0
  stage(B, gn0,       0, 32768);   // T0.B-H0 -> buf0
  stage(A, gm0 + 128, 0, 8192);    // T0.A-H1 -> buf0
  stage(B, gn0 + 128, 0, 40960);   // T0.B-H1 -> buf0
  stage(A, gm0,      64, 16384);   // T1.A-H0 -> buf1
  stage(B, gn0,      64, 49152);   // T1.B-H0 -> buf1
  FENCE;
  asm volatile("s_waitcnt vmcnt(8)" ::: "memory");
  __builtin_amdgcn_s_barrier();
  FENCE;
  READ_AF2(af0, 0, 0, 0)   // first half of P1's fragments
  READ_BF2(bf0, 0, 0, 0)

  for (int it = 0; it < 32; ++it) {
    const int k1 = ((2 * it + 1) * 64) & 4095;
    const int k2 = ((2 * it + 2) * 64) & 4095;
    const int k3 = ((2 * it + 3) * 64) & 4095;
    // ---- P1 (buf0, QM0xQN0) ----
    READ_AF2(af0, 0, 0, 1) READ_BF2(bf0, 0, 0, 1)
    PHASE_BEGIN(A, gm0 + 128, k1, 24576, 6)    // (T+1).A-H1 -> buf1
    MFMA16(0, 0, af0, bf0)
    READ_BF2(bf1, 1, 0, 0) READ_BF2(bf1, 1, 0, 1)
    PHASE_END
    // ---- P2 (buf0, QM0xQN1) ----
    PHASE_BEGIN(B, gn0 + 128, k1, 57344, 63)   // (T+1).B-H1 -> buf1
    MFMA16(0, 1, af0, bf1)
    READ_AF2(af1, 1, 0, 0)
    PHASE_END
    // ---- P3 (buf0, QM1xQN1) ----
    READ_AF2(af1, 1, 0, 1)
    PHASE_BEGIN(A, gm0,       k2, 0,     63)   // (T+2).A-H0 -> buf0
    MFMA16(1, 1, af1, bf1)
    PHASE_END
    // ---- P4 (buf0, QM1xQN0) ----
    PHASE_BEGIN(B, gn0,       k2, 32768, 8)    // (T+2).B-H0 -> buf0
    MFMA16(1, 0, af1, bf0)
    READ_AF2(af0, 0, 1, 0) READ_BF2(bf0, 0, 1, 0)
    PHASE_END
    // ---- P5 (buf1, QM0xQN0) ----
    READ_AF2(af0, 0, 1, 1) READ_BF2(bf0, 0, 1, 1)
    PHASE_BEGIN(A, gm0 + 128, k2, 8192,  6)    // (T+2).A-H1 -> buf0
    MFMA16(0, 0, af0, bf0)
    READ_BF2(bf1, 1, 1, 0) READ_BF2(bf1, 1, 1, 1)
    PHASE_END
    // ---- P6 (buf1, QM0xQN1) ----
    PHASE_BEGIN(B, gn0 + 128, k2, 40960, 63)   // (T+2).B-H1 -> buf0
    MFMA16(0, 1, af0, bf1)
    READ_AF2(af1, 1, 1, 0)
    PHASE_END
    // ---- P7 (buf1, QM1xQN1) ----
    READ_AF2(af1, 1, 1, 1)
    PHASE_BEGIN(A, gm0,       k3, 16384, 63)   // (T+3).A-H0 -> buf1
    MFMA16(1, 1, af1, bf1)
    PHASE_END
    // ---- P8 (buf1, QM1xQN0) ----
    PHASE_BEGIN(B, gn0,       k3, 49152, 8)    // (T+3).B-H0 -> buf1
    MFMA16(1, 0, af1, bf0)
    READ_AF2(af0, 0, 0, 0) READ_BF2(bf0, 0, 0, 0)   // next iter's P1 frags
    PHASE_END
  }
#undef PHASE_BEGIN
#undef PHASE_END
#undef MFMA16
#undef READ_AF2
#undef READ_BF2
  asm volatile("s_waitcnt vmcnt(0)" ::: "memory");

  // epilogue (nontemporal: C is write-once, keep operands in L3)
  const int orow = kqi * 4;
#pragma unroll
  for (int qm = 0; qm < 2; ++qm)
#pragma unroll
    for (int qn = 0; qn < 2; ++qn)
#pragma unroll
      for (int mi = 0; mi < 4; ++mi)
#pragma unroll
        for (int ni = 0; ni < 2; ++ni) {
          const int row0 = gm0 + qm * 128 + wm * 64 + mi * 16 + orow;
          const int col  = gn0 + qn * 128 + wn * 32 + ni * 16 + fr;
          f32x4 v = acc[qm][qn][mi][ni];
#pragma unroll
          for (int r = 0; r < 4; ++r)
            __builtin_nontemporal_store(v[r], &C[(size_t)(row0 + r) * OUT_DIM + col]);
        }
}

// ---------------- launch ----------------
extern "C" void kernel_launch(void* const* d_in, const int* in_sizes, int n_in,
                              void* d_out, int out_size, void* d_ws, size_t ws_size,
                              hipStream_t stream) {
  const float* x      = (const float*)d_in[0];
  const float* SU     = (const float*)d_in[1];
  const float* SV     = (const float*)d_in[2];
  const float* wscale = (const float*)d_in[3];
  const int* trellis  = (const int*)d_in[4];
  float* out = (float*)d_out;

  // ws: xq bf16 [0,64Mi); wq bf16 [64Mi,96Mi).
  char* ws = (char*)d_ws;
  unsigned short* xq = (unsigned short*)ws;
  unsigned short* wq = (unsigned short*)(ws + (size_t)67108864);

  // d_out (128 MiB) reuse: xh bf16 [0,64Mi); wdec bf16 [64Mi,96Mi);
  // pmin/pmax/scale/zero in [96Mi,..) — consumed by quant before the GEMM
  // overwrites d_out.
  unsigned short* xh   = (unsigned short*)out;
  unsigned short* wdec = (unsigned short*)out + (size_t)33554432;
  char* outb = (char*)out;
  float* pmin  = (float*)(outb + (size_t)100663296);             // 96Mi, 512 KiB
  float* pmax  = (float*)(outb + (size_t)100663296 + 524288);    // 512 KiB
  float* scale = (float*)(outb + (size_t)100663296 + 1048576);   // 16 KiB
  float* zero  = (float*)(outb + (size_t)100663296 + 1064960);   // 16 KiB

  hipLaunchKernelGGL(pre1_kernel, dim3(12288), dim3(256), 0, stream,
                     x, SU, xh, trellis, wdec);
  hipLaunchKernelGGL(pre2_kernel, dim3(4352), dim3(256), 0, stream,
                     xh, pmin, pmax, wdec, SV, wscale, wq);
  hipLaunchKernelGGL(minmax_fin_kernel, dim3(16), dim3(256), 0, stream,
                     pmin, pmax, scale, zero);
  hipLaunchKernelGGL(quant_kernel, dim3(2048), dim3(256), 0, stream, xh, scale, zero, xq);
  hipLaunchKernelGGL(gemm256_kernel, dim3((M_ROWS / 256) * (OUT_DIM / 256)), dim3(512), 0,
                     stream, xq, wq, out);
}

// Round 12
// 322.076 us; speedup vs baseline: 1.0396x; 1.0396x over previous
//
#include <hip/hip_runtime.h>
#include <hip/hip_bf16.h>
#include <stdint.h>

#define IN_DIM 4096
#define OUT_DIM 4096
#define M_ROWS 8192   // 4 * 2048

typedef __attribute__((ext_vector_type(8))) short s16x8;
typedef __attribute__((ext_vector_type(4))) float f32x4;

__device__ __forceinline__ unsigned short f2bf(float f) {
  uint32_t u = __float_as_uint(f);
  uint32_t r = (u + 0x7fffu + ((u >> 16) & 1u)) >> 16;  // RNE
  return (unsigned short)r;
}
__device__ __forceinline__ float b2f(unsigned short u) {
  return __uint_as_float((uint32_t)u << 16);
}

__device__ __forceinline__ void async16(void* lds, const void* g) {
  __builtin_amdgcn_global_load_lds(
      (const __attribute__((address_space(1))) unsigned int*)g,
      (__attribute__((address_space(3))) unsigned int*)lds, 16, 0, 0);
}

#define FENCE asm volatile("" ::: "memory")

// in-register H16 (4 radix-2 stages, all indices compile-time)
__device__ __forceinline__ void h16(float (&v)[16]) {
#pragma unroll
  for (int h = 1; h < 16; h <<= 1) {
#pragma unroll
    for (int g = 0; g < 8; ++g) {
      int r = g & (h - 1);
      int i0 = ((g & ~(h - 1)) << 1) | r;
      float a = v[i0], b = v[i0 + h];
      v[i0] = a + b;
      v[i0 + h] = a - b;
    }
  }
}

// radix-4 butterfly over t[64][65] columns
#define W_RADIX4(TARR)                                                     \
  for (int h = 1; h < 64; h <<= 2) {                                       \
    __syncthreads();                                                       \
    _Pragma("unroll") for (int j = 0; j < 4; ++j) {                        \
      int g2 = j * 256 + tid;                                              \
      int c = g2 & 63, u = g2 >> 6;                                        \
      int r = u & (h - 1);                                                 \
      int i0 = ((u & ~(h - 1)) << 2) | r;                                  \
      float a = TARR[i0][c], b2 = TARR[i0 + h][c];                         \
      float c2 = TARR[i0 + 2 * h][c], d = TARR[i0 + 3 * h][c];             \
      float y0 = a + b2, y1 = a - b2, y2 = c2 + d, y3 = c2 - d;            \
      TARR[i0][c] = y0 + y2;                                               \
      TARR[i0 + h][c] = y1 + y3;                                           \
      TARR[i0 + 2 * h][c] = y0 - y2;                                       \
      TARR[i0 + 3 * h][c] = y1 - y3;                                       \
    }                                                                      \
  }                                                                        \
  __syncthreads();

// ---- K1: fwht_x (blocks 0..8191) || trellis-decode + inner W-FWHT (8192..12287)
// w_inner blocks remapped so each ohi-group's 64 blocks land on ONE XCD
// (trellis rows shared by the group -> L2 line fetched once per group).
__global__ __launch_bounds__(256) void pre1_kernel(
    const float* __restrict__ x, const float* __restrict__ SU,
    unsigned short* __restrict__ xh,
    const int* __restrict__ trellis, unsigned short* __restrict__ wdec) {
  __shared__ __align__(16) char smem[17408];
  const int tid = threadIdx.x;
  if (blockIdx.x < 8192) {
    // ---------- xh = bf16(fwht(x * SU)) = H16 (x) H16 (x) H16, one row ----------
    float* s = (float*)smem;  // padded: addr(i) = i + (i>>4), 4352 floats
    const int row = blockIdx.x;
    const int t = tid;
    float v[16];
    const float* xr = x + (size_t)row * IN_DIM;
#pragma unroll
    for (int a = 0; a < 16; ++a) {
      int i = a * 256 + t;
      v[a] = __builtin_nontemporal_load(&xr[i]) * SU[i];  // x: single-use stream
    }
    h16(v);  // over a
#pragma unroll
    for (int a = 0; a < 16; ++a) {
      int i = a * 256 + t;
      s[i + (i >> 4)] = v[a];
    }
    __syncthreads();
    const int A = t >> 4, C = t & 15;
#pragma unroll
    for (int b = 0; b < 16; ++b) {
      int i = A * 256 + b * 16 + C;
      v[b] = s[i + (i >> 4)];
    }
    h16(v);  // over b
    __syncthreads();
#pragma unroll
    for (int b = 0; b < 16; ++b) {
      int i = A * 256 + b * 16 + C;
      s[i + (i >> 4)] = v[b];
    }
    __syncthreads();
#pragma unroll
    for (int c = 0; c < 16; ++c) {
      int i = t * 16 + c;
      v[c] = s[i + (i >> 4)];
    }
    h16(v);  // over c
    unsigned short ob[16];
#pragma unroll
    for (int c = 0; c < 16; ++c) ob[c] = f2bf(v[c] * 0.015625f);
    s16x8* dst = (s16x8*)(xh + (size_t)row * IN_DIM + t * 16);
    dst[0] = *(s16x8*)&ob[0];
    dst[1] = *(s16x8*)&ob[8];
  } else {
    // ---------- trellis decode + FWHT over OUT bits 0..5 (bf16 out) ----------
    float (*t)[65] = (float(*)[65])smem;  // 64x65 floats
    const int b2 = blockIdx.x - 8192;     // 0..4095
    // XCD-group remap: ohi's 64 blocks all have b2 % 8 == ohi % 8 -> same XCD
    const int slot = b2 & 7;
    const int q = b2 >> 3;          // 0..511
    const int it = q & 63;
    const int ohi = (q >> 6) * 8 + slot;
    const float g = 0.44721359549995793f;  // 1/sqrt(5)
#pragma unroll
    for (int j = 0; j < 2; ++j) {
      int wi = j * 256 + tid;
      int r = wi >> 3, wc = wi & 7;
      int word = __builtin_nontemporal_load(
          &trellis[(size_t)(ohi * 64 + r) * 512 + it * 8 + wc]);
#pragma unroll
      for (int jj = 0; jj < 8; ++jj) {
        int code = (word >> (14 - 2 * jj)) & 3;
        t[r][wc * 8 + jj] = (float)(2 * code - 3) * g;
      }
    }
    W_RADIX4(t)
#pragma unroll
    for (int j = 0; j < 16; ++j) {
      int e = j * 256 + tid;
      int r = e >> 6, c = e & 63;
      wdec[((size_t)(ohi * 64 + r)) * IN_DIM + it * 64 + c] = f2bf(t[r][c]);
    }
  }
}

// ---- K2: per-channel min/max partials (blocks 0..255) || outer W-FWHT (256..4351)
__global__ __launch_bounds__(256) void pre2_kernel(
    const unsigned short* __restrict__ xh,
    float* __restrict__ pmin, float* __restrict__ pmax,
    const unsigned short* __restrict__ wdec, const float* __restrict__ SV,
    const float* __restrict__ wscale, unsigned short* __restrict__ wq) {
  __shared__ __align__(16) char smem[16640];
  const int tid = threadIdx.x;
  if (blockIdx.x < 256) {
    // ---------- min/max over 256-row chunk, 2 channels/thread ----------
    const int rc = blockIdx.x >> 3;   // 0..31 row-chunk of 256 rows
    const int cb = blockIdx.x & 7;    // 0..7 channel block of 512
    const int ch0 = cb * 512 + tid * 2;
    float mn0 = 3.4e38f, mx0 = -3.4e38f, mn1 = 3.4e38f, mx1 = -3.4e38f;
    const unsigned int* base =
        (const unsigned int*)(xh + (size_t)rc * 256 * IN_DIM + ch0);
    for (int r = 0; r < 256; ++r) {
      unsigned int u = base[(size_t)r * (IN_DIM / 2)];
      float v0 = __uint_as_float(u << 16);
      float v1 = __uint_as_float(u & 0xffff0000u);
      mn0 = fminf(mn0, v0); mx0 = fmaxf(mx0, v0);
      mn1 = fminf(mn1, v1); mx1 = fmaxf(mx1, v1);
    }
    pmin[rc * IN_DIM + ch0] = mn0;
    pmin[rc * IN_DIM + ch0 + 1] = mn1;
    pmax[rc * IN_DIM + ch0] = mx0;
    pmax[rc * IN_DIM + ch0 + 1] = mx1;
  } else {
    // ---------- FWHT over OUT bits 6..11 + 1/64 + SV + group scales ----------
    float (*t)[65] = (float(*)[65])smem;
    const int b = blockIdx.x - 256;
    const int olo = b >> 6;
    const int it  = b & 63;
#pragma unroll
    for (int j = 0; j < 16; ++j) {
      int e = j * 256 + tid;
      int r = e >> 6, c = e & 63;
      t[r][c] = b2f(__builtin_nontemporal_load(
          &wdec[((size_t)(r * 64 + olo)) * IN_DIM + it * 64 + c]));  // last use
    }
    W_RADIX4(t)
#pragma unroll
    for (int j = 0; j < 16; ++j) {
      int e = j * 256 + tid;
      int r = e >> 6, c = e & 63;
      int o = r * 64 + olo;
      int i = it * 64 + c;
      float val = t[r][c] * 0.015625f * SV[o] * wscale[(o << 4) + (i >> 8)];
      wq[(size_t)o * IN_DIM + i] = f2bf(val);
    }
  }
}

// ---------------- K3: reduce partials -> scale/zero ----------------
__global__ void minmax_fin_kernel(const float* __restrict__ pmin, const float* __restrict__ pmax,
                                  float* __restrict__ scale, float* __restrict__ zero) {
  int ch = blockIdx.x * 256 + threadIdx.x;
  float mn = 3.4e38f, mx = -3.4e38f;
  for (int rc = 0; rc < 32; ++rc) {
    mn = fminf(mn, pmin[rc * IN_DIM + ch]);
    mx = fmaxf(mx, pmax[rc * IN_DIM + ch]);
  }
  float sc = fmaxf((mx - mn) / 255.0f, 1e-8f);
  float zp = rintf(-mn / sc);  // rintf = half-to-even = jnp.round
  scale[ch] = sc;
  zero[ch] = zp;
}

// ---------------- K4: fake-quant + bf16 cast ----------------
__global__ void quant_kernel(const unsigned short* __restrict__ xh,
                             const float* __restrict__ scale, const float* __restrict__ zero,
                             unsigned short* __restrict__ xq) {
  const int total8 = M_ROWS * IN_DIM / 8;
  for (int i8 = blockIdx.x * blockDim.x + threadIdx.x; i8 < total8;
       i8 += gridDim.x * blockDim.x) {
    int c8 = i8 & (IN_DIM / 8 - 1);
    s16x8 v = __builtin_nontemporal_load(&((const s16x8*)xh)[i8]);  // last use of xh
    unsigned short o[8];
#pragma unroll
    for (int j = 0; j < 8; ++j) {
      float sc = scale[c8 * 8 + j];
      float zp = zero[c8 * 8 + j];
      float f = b2f((unsigned short)v[j]);
      float q = fminf(fmaxf(rintf(f / sc) + zp, 0.f), 255.f);
      o[j] = f2bf((q - zp) * sc);
    }
    ((s16x8*)xq)[i8] = *(s16x8*)&o[0];
  }
}

// ---------------- K5: 256x256 8-phase bf16 GEMM (round-6 proven; plain C stores)
__global__ __launch_bounds__(512, 2) void gemm256_kernel(
    const unsigned short* __restrict__ A, const unsigned short* __restrict__ B,
    float* __restrict__ C) {
  __shared__ __align__(16) unsigned short lds[65536];  // 128 KiB
  const int tid  = threadIdx.x;
  const int lane = tid & 63;
  const int wave = tid >> 6;
  const int wm = wave >> 2, wn = wave & 3;
  const int fr = lane & 15, kqi = lane >> 4;
  const int swz = fr & 7;

  // XCD-aware bijective swizzle (nwg=512, 512%8==0)
  const int b  = blockIdx.x;
  const int wg = (b & 7) * 64 + (b >> 3);
  const int bm = wg >> 4, bn = wg & 15;
  const int gm0 = bm * 256, gn0 = bn * 256;

  f32x4 acc[2][2][4][2] = {};  // [qm][qn][mi][ni]
  s16x8 af0[4][2], af1[4][2];  // QM0 / QM1 fragment buffers [mi][kk]
  s16x8 bf0[2][2], bf1[2][2];  // QN0 / QN1 fragment buffers [ni][kk]

  const int F0 = tid, F1 = 512 + tid;
  const int rh0 = F0 >> 3, s0 = (F0 & 7) ^ (rh0 & 7);
  const int rh1 = F1 >> 3, s1 = (F1 & 7) ^ (rh1 & 7);
  auto stage = [&](const unsigned short* gbase, int grow0, int kcol, int ldsoff) {
    async16((void*)&lds[ldsoff + F0 * 8],
            (const void*)(gbase + (size_t)(grow0 + rh0) * IN_DIM + kcol + s0 * 8));
    async16((void*)&lds[ldsoff + F1 * 8],
            (const void*)(gbase + (size_t)(grow0 + rh1) * IN_DIM + kcol + s1 * 8));
  };

#define READ_AF2(DST, QM, TBUF, MIH)                                                      \
  {                                                                                       \
    const int abase = (TBUF) * 16384 + (QM) * 8192;                                       \
    _Pragma("unroll") for (int kk = 0; kk < 2; ++kk)                                      \
      _Pragma("unroll") for (int mi = 2 * (MIH); mi < 2 * (MIH) + 2; ++mi) {              \
        int rh = wm * 64 + mi * 16 + fr;                                                  \
        DST[mi][kk] = *(const s16x8*)&lds[abase + rh * 64 + (((kk * 4 + kqi) ^ swz) * 8)];\
      }                                                                                   \
  }
#define READ_BF2(DST, QN, TBUF, NI)                                                       \
  {                                                                                       \
    const int bbase = 32768 + (TBUF) * 16384 + (QN) * 8192;                               \
    const int rh = wn * 32 + (NI) * 16 + fr;                                              \
    _Pragma("unroll") for (int kk = 0; kk < 2; ++kk)                                      \
      DST[NI][kk] = *(const s16x8*)&lds[bbase + rh * 64 + (((kk * 4 + kqi) ^ swz) * 8)];  \
  }
#define MFMA16(QM, QN, AF, BF)                                                            \
    _Pragma("unroll") for (int kk = 0; kk < 2; ++kk)                                      \
      _Pragma("unroll") for (int mi = 0; mi < 4; ++mi)                                    \
        _Pragma("unroll") for (int ni = 0; ni < 2; ++ni)                                  \
          acc[QM][QN][mi][ni] = __builtin_amdgcn_mfma_f32_16x16x32_bf16(                  \
              AF[mi][kk], BF[ni][kk], acc[QM][QN][mi][ni], 0, 0, 0);
#define PHASE_BEGIN(SGBASE, SGROW0, SKCOL, SLDSOFF, VM)                                   \
    stage(SGBASE, SGROW0, SKCOL, SLDSOFF);                                                \
    FENCE;                                                                                \
    asm volatile("s_waitcnt vmcnt(" #VM ")" ::: "memory");                                \
    __builtin_amdgcn_s_barrier();                                                         \
    FENCE;                                                                                \
    __builtin_amdgcn_s_setprio(1);
#define PHASE_END                                                                         \
    __builtin_amdgcn_s_setprio(0);                                                        \
    FENCE;                                                                                \
    __builtin_amdgcn_s_barrier();                                                         \
    FENCE;

  // prologue: stage T0 fully + T1 half0s; vmcnt(8) completes T0.A-H0/B-H0
  stage(A, gm0,       0, 0);       // T0.A-H0 -> buf0
  stage(B, gn0,       0, 32768);   // T0.B-H0 -> buf0
  stage(A, gm0 + 128, 0, 8192);    // T0.A-H1 -> buf0
  stage(B, gn0 + 128, 0, 40960);   // T0.B-H1 -> buf0
  stage(A, gm0,      64, 16384);   // T1.A-H0 -> buf1
  stage(B, gn0,      64, 49152);   // T1.B-H0 -> buf1
  FENCE;
  asm volatile("s_waitcnt vmcnt(8)" ::: "memory");
  __builtin_amdgcn_s_barrier();
  FENCE;
  READ_AF2(af0, 0, 0, 0)   // first half of P1's fragments
  READ_BF2(bf0, 0, 0, 0)

  for (int it = 0; it < 32; ++it) {
    const int k1 = ((2 * it + 1) * 64) & 4095;
    const int k2 = ((2 * it + 2) * 64) & 4095;
    const int k3 = ((2 * it + 3) * 64) & 4095;
    // ---- P1 (buf0, QM0xQN0) ----
    READ_AF2(af0, 0, 0, 1) READ_BF2(bf0, 0, 0, 1)
    PHASE_BEGIN(A, gm0 + 128, k1, 24576, 6)    // (T+1).A-H1 -> buf1
    MFMA16(0, 0, af0, bf0)
    READ_BF2(bf1, 1, 0, 0) READ_BF2(bf1, 1, 0, 1)
    PHASE_END
    // ---- P2 (buf0, QM0xQN1) ----
    PHASE_BEGIN(B, gn0 + 128, k1, 57344, 63)   // (T+1).B-H1 -> buf1
    MFMA16(0, 1, af0, bf1)
    READ_AF2(af1, 1, 0, 0)
    PHASE_END
    // ---- P3 (buf0, QM1xQN1) ----
    READ_AF2(af1, 1, 0, 1)
    PHASE_BEGIN(A, gm0,       k2, 0,     63)   // (T+2).A-H0 -> buf0
    MFMA16(1, 1, af1, bf1)
    PHASE_END
    // ---- P4 (buf0, QM1xQN0) ----
    PHASE_BEGIN(B, gn0,       k2, 32768, 8)    // (T+2).B-H0 -> buf0
    MFMA16(1, 0, af1, bf0)
    READ_AF2(af0, 0, 1, 0) READ_BF2(bf0, 0, 1, 0)
    PHASE_END
    // ---- P5 (buf1, QM0xQN0) ----
    READ_AF2(af0, 0, 1, 1) READ_BF2(bf0, 0, 1, 1)
    PHASE_BEGIN(A, gm0 + 128, k2, 8192,  6)    // (T+2).A-H1 -> buf0
    MFMA16(0, 0, af0, bf0)
    READ_BF2(bf1, 1, 1, 0) READ_BF2(bf1, 1, 1, 1)
    PHASE_END
    // ---- P6 (buf1, QM0xQN1) ----
    PHASE_BEGIN(B, gn0 + 128, k2, 40960, 63)   // (T+2).B-H1 -> buf0
    MFMA16(0, 1, af0, bf1)
    READ_AF2(af1, 1, 1, 0)
    PHASE_END
    // ---- P7 (buf1, QM1xQN1) ----
    READ_AF2(af1, 1, 1, 1)
    PHASE_BEGIN(A, gm0,       k3, 16384, 63)   // (T+3).A-H0 -> buf1
    MFMA16(1, 1, af1, bf1)
    PHASE_END
    // ---- P8 (buf1, QM1xQN0) ----
    PHASE_BEGIN(B, gn0,       k3, 49152, 8)    // (T+3).B-H0 -> buf1
    MFMA16(1, 0, af1, bf0)
    READ_AF2(af0, 0, 0, 0) READ_BF2(bf0, 0, 0, 0)   // next iter's P1 frags
    PHASE_END
  }
#undef PHASE_BEGIN
#undef PHASE_END
#undef MFMA16
#undef READ_AF2
#undef READ_BF2
  asm volatile("s_waitcnt vmcnt(0)" ::: "memory");

  // epilogue (plain stores — NT stores measured +28% WRITE_SIZE, -9 us regress)
  const int orow = kqi * 4;
#pragma unroll
  for (int qm = 0; qm < 2; ++qm)
#pragma unroll
    for (int qn = 0; qn < 2; ++qn)
#pragma unroll
      for (int mi = 0; mi < 4; ++mi)
#pragma unroll
        for (int ni = 0; ni < 2; ++ni) {
          const int row0 = gm0 + qm * 128 + wm * 64 + mi * 16 + orow;
          const int col  = gn0 + qn * 128 + wn * 32 + ni * 16 + fr;
          f32x4 v = acc[qm][qn][mi][ni];
#pragma unroll
          for (int r = 0; r < 4; ++r)
            C[(size_t)(row0 + r) * OUT_DIM + col] = v[r];
        }
}

// ---------------- launch ----------------
extern "C" void kernel_launch(void* const* d_in, const int* in_sizes, int n_in,
                              void* d_out, int out_size, void* d_ws, size_t ws_size,
                              hipStream_t stream) {
  const float* x      = (const float*)d_in[0];
  const float* SU     = (const float*)d_in[1];
  const float* SV     = (const float*)d_in[2];
  const float* wscale = (const float*)d_in[3];
  const int* trellis  = (const int*)d_in[4];
  float* out = (float*)d_out;

  // ws: xq bf16 [0,64Mi); wq bf16 [64Mi,96Mi).
  char* ws = (char*)d_ws;
  unsigned short* xq = (unsigned short*)ws;
  unsigned short* wq = (unsigned short*)(ws + (size_t)67108864);

  // d_out (128 MiB) reuse: xh bf16 [0,64Mi); wdec bf16 [64Mi,96Mi);
  // pmin/pmax/scale/zero in [96Mi,..) — consumed by quant before the GEMM
  // overwrites d_out.
  unsigned short* xh   = (unsigned short*)out;
  unsigned short* wdec = (unsigned short*)out + (size_t)33554432;
  char* outb = (char*)out;
  float* pmin  = (float*)(outb + (size_t)100663296);             // 96Mi, 512 KiB
  float* pmax  = (float*)(outb + (size_t)100663296 + 524288);    // 512 KiB
  float* scale = (float*)(outb + (size_t)100663296 + 1048576);   // 16 KiB
  float* zero  = (float*)(outb + (size_t)100663296 + 1064960);   // 16 KiB

  hipLaunchKernelGGL(pre1_kernel, dim3(12288), dim3(256), 0, stream,
                     x, SU, xh, trellis, wdec);
  hipLaunchKernelGGL(pre2_kernel, dim3(4352), dim3(256), 0, stream,
                     xh, pmin, pmax, wdec, SV, wscale, wq);
  hipLaunchKernelGGL(minmax_fin_kernel, dim3(16), dim3(256), 0, stream,
                     pmin, pmax, scale, zero);
  hipLaunchKernelGGL(quant_kernel, dim3(2048), dim3(256), 0, stream, xh, scale, zero, xq);
  hipLaunchKernelGGL(gemm256_kernel, dim3((M_ROWS / 256) * (OUT_DIM / 256)), dim3(512), 0,
                     stream, xq, wq, out);
}